// Round 1
// baseline (64859.436 us; speedup 1.0000x reference)
//
#include <hip/hip_runtime.h>
#include <cmath>

#define NV 32000
#define NE 512
#define NH 1024
#define NTX 2048
#define NTY 512
#define NWG 256
#define TPB 512

typedef float vf4 __attribute__((ext_vector_type(4)));
typedef unsigned long long u64;

// ---------- helpers ----------
__device__ inline float sigm(float x){ return 1.0f/(1.0f + expf(-x)); }

__device__ inline float wred(float v){
  #pragma unroll
  for (int m = 32; m; m >>= 1) v += __shfl_xor(v, m, 64);
  return v;
}

// plain (cached) 16-float load, 16B-vectorized
__device__ inline void ld16(const float* __restrict__ p, float* d){
  vf4 a = *(const vf4*)p, b = *(const vf4*)(p+4), c = *(const vf4*)(p+8), e = *(const vf4*)(p+12);
  d[0]=a.x; d[1]=a.y; d[2]=a.z; d[3]=a.w;
  d[4]=b.x; d[5]=b.y; d[6]=b.z; d[7]=b.w;
  d[8]=c.x; d[9]=c.y; d[10]=c.z; d[11]=c.w;
  d[12]=e.x; d[13]=e.y; d[14]=e.z; d[15]=e.w;
}

// coherent (agent-scope, LLC-served) 16-float load: correct across XCDs
__device__ inline void coh16(const float* p, float* d){
  #pragma unroll
  for (int k = 0; k < 16; ++k)
    d[k] = __hip_atomic_load(p + k, __ATOMIC_RELAXED, __HIP_MEMORY_SCOPE_AGENT);
}

__device__ inline void sto(float* p, float v){
  __hip_atomic_store(p, v, __ATOMIC_RELAXED, __HIP_MEMORY_SCOPE_AGENT);
}

// grid barrier: monotonic counter, 256 arrivals, agent scope (LLC coherence point)
__device__ inline void gbar(unsigned* cnt, unsigned target){
  __syncthreads();
  if (threadIdx.x == 0){
    __hip_atomic_fetch_add(cnt, 1u, __ATOMIC_ACQ_REL, __HIP_MEMORY_SCOPE_AGENT);
    while (__hip_atomic_load(cnt, __ATOMIC_ACQUIRE, __HIP_MEMORY_SCOPE_AGENT) < target)
      __builtin_amdgcn_s_sleep(2);
  }
  __syncthreads();
}

// ws layout (bytes):
//   0   : cnt_enc
//   128 : cnt_dec
//   1024: h0buf[2][1024] f32
//   +8K : h1buf[2][1024]
//   +8K : ysbuf[2][1024]
//   +8K : f1buf[1024]
//   +4K : f2buf[1024]
//   33792: parts[256] u64

// ---------- encoder: persistent, layers 0/1 pipelined, + fc1/fc2 ----------
__global__ __launch_bounds__(TPB, 2) void enc_kernel(
    const int* __restrict__ x, const float* __restrict__ emb,
    const float* __restrict__ Wih0, const float* __restrict__ Whh0, const float* __restrict__ b0,
    const float* __restrict__ Wih1, const float* __restrict__ Whh1, const float* __restrict__ b1,
    const float* __restrict__ fc1w, const float* __restrict__ fc1b,
    const float* __restrict__ fc2w, const float* __restrict__ fc2b,
    char* __restrict__ ws)
{
  unsigned* cnt = (unsigned*)ws;
  float* h0buf = (float*)(ws + 1024);
  float* h1buf = h0buf + 2048;
  float* ysbuf = h1buf + 2048;
  float* f1buf = ysbuf + 2048;
  float* f2buf = f1buf + 1024;

  const int tid = threadIdx.x, wg = blockIdx.x;
  const int wid = tid >> 6, lane = tid & 63;
  const bool isA = (wid < 4);          // waves 0-3: layer0, waves 4-7: layer1
  const int j = wg*4 + (wid & 3);      // 0..1023 : hidden index owned by this wave
  unsigned ph = 0;

  // register-resident weights (shared arrays across branches -> one allocation)
  float wa[4][16], wb[4][16], bias[4];
  if (isA){
    #pragma unroll
    for (int g = 0; g < 4; ++g){
      ld16(Whh0 + (size_t)(j + g*1024)*1024 + lane*16, wa[g]);
      const float* r2 = Wih0 + (size_t)(j + g*1024)*512 + lane*8;
      vf4 u0 = *(const vf4*)r2, u1 = *(const vf4*)(r2+4);
      wb[g][0]=u0.x; wb[g][1]=u0.y; wb[g][2]=u0.z; wb[g][3]=u0.w;
      wb[g][4]=u1.x; wb[g][5]=u1.y; wb[g][6]=u1.z; wb[g][7]=u1.w;
      #pragma unroll
      for (int k = 8; k < 16; ++k) wb[g][k] = 0.f;
      bias[g] = b0[j + g*1024];
    }
  } else {
    #pragma unroll
    for (int g = 0; g < 4; ++g){
      ld16(Wih1 + (size_t)(j + g*1024)*1024 + lane*16, wa[g]);
      ld16(Whh1 + (size_t)(j + g*1024)*1024 + lane*16, wb[g]);
      bias[g] = b1[j + g*1024];
    }
  }

  float c = 0.f;
  if (lane == 0){
    if (isA) sto(&h0buf[j], 0.f);
    else     sto(&h1buf[j], 0.f);
  }
  ph++; gbar(cnt, ph*NWG);

  // embedding prefetch for t = 0
  float xe[8] = {0,0,0,0,0,0,0,0};
  if (isA){
    const float* e = emb + (size_t)x[0]*NE + lane*8;
    vf4 a = *(const vf4*)e, b2 = *(const vf4*)(e+4);
    xe[0]=a.x; xe[1]=a.y; xe[2]=a.z; xe[3]=a.w;
    xe[4]=b2.x; xe[5]=b2.y; xe[6]=b2.z; xe[7]=b2.w;
  }

  for (int t = 0; t <= NTX; ++t){
    if (isA){
      if (t < NTX){
        float hs[16]; coh16(h0buf + (t&1)*1024 + lane*16, hs);
        float xc[8];
        #pragma unroll
        for (int k = 0; k < 8; ++k) xc[k] = xe[k];
        if (t + 1 < NTX){    // prefetch next embedding row
          const float* e = emb + (size_t)x[t+1]*NE + lane*8;
          vf4 a = *(const vf4*)e, b2 = *(const vf4*)(e+4);
          xe[0]=a.x; xe[1]=a.y; xe[2]=a.z; xe[3]=a.w;
          xe[4]=b2.x; xe[5]=b2.y; xe[6]=b2.z; xe[7]=b2.w;
        }
        float p[4];
        #pragma unroll
        for (int g = 0; g < 4; ++g){
          float s = 0.f;
          #pragma unroll
          for (int k = 0; k < 8; ++k)  s += wb[g][k]*xc[k];
          #pragma unroll
          for (int k = 0; k < 16; ++k) s += wa[g][k]*hs[k];
          p[g] = s;
        }
        #pragma unroll
        for (int g = 0; g < 4; ++g) p[g] = wred(p[g]) + bias[g];
        float ig = sigm(p[0]), fg = sigm(p[1]), gg = tanhf(p[2]), og = sigm(p[3]);
        c = fg*c + ig*gg;
        float hn = og * tanhf(c);
        if (lane == 0){
          sto(&h0buf[((t&1)^1)*1024 + j], hn);
          sto(&ysbuf[(t&1)*1024 + j], hn);
        }
      }
    } else {
      if (t >= 1){
        const int t1 = t - 1;
        float ys[16]; coh16(ysbuf + (t1&1)*1024 + lane*16, ys);
        float hs[16]; coh16(h1buf + (t1&1)*1024 + lane*16, hs);
        float p[4];
        #pragma unroll
        for (int g = 0; g < 4; ++g){
          float s = 0.f;
          #pragma unroll
          for (int k = 0; k < 16; ++k) s += wa[g][k]*ys[k];
          #pragma unroll
          for (int k = 0; k < 16; ++k) s += wb[g][k]*hs[k];
          p[g] = s;
        }
        #pragma unroll
        for (int g = 0; g < 4; ++g) p[g] = wred(p[g]) + bias[g];
        float ig = sigm(p[0]), fg = sigm(p[1]), gg = tanhf(p[2]), og = sigm(p[3]);
        c = fg*c + ig*gg;
        float hn = og * tanhf(c);
        if (lane == 0) sto(&h1buf[((t1&1)^1)*1024 + j], hn);
      }
    }
    ph++; gbar(cnt, ph*NWG);
  }

  // fc1: h_last is h1buf parity 0 (last write t1=2047 -> wp=0)
  if (isA){
    float hs[16]; coh16(h1buf + lane*16, hs);
    float wv[16]; ld16(fc1w + (size_t)j*1024 + lane*16, wv);
    float s = 0.f;
    #pragma unroll
    for (int k = 0; k < 16; ++k) s += wv[k]*hs[k];
    s = wred(s) + fc1b[j];
    if (lane == 0) sto(&f1buf[j], fmaxf(s, 0.f));
  }
  ph++; gbar(cnt, ph*NWG);
  if (isA){
    float fs[16]; coh16(f1buf + lane*16, fs);
    float wv[16]; ld16(fc2w + (size_t)j*1024 + lane*16, wv);
    float s = 0.f;
    #pragma unroll
    for (int k = 0; k < 16; ++k) s += wv[k]*fs[k];
    s = wred(s) + fc2b[j];
    if (lane == 0) sto(&f2buf[j], fmaxf(s, 0.f));
  }
}

// ---------- decoder: persistent, 511 greedy steps ----------
__global__ __launch_bounds__(TPB, 2) void dec_kernel(
    const int* __restrict__ y,
    const float* __restrict__ dWih0, const float* __restrict__ dWhh0, const float* __restrict__ db0,
    const float* __restrict__ dWih1, const float* __restrict__ dWhh1, const float* __restrict__ db1,
    const float* __restrict__ out_w, const float* __restrict__ out_b,
    float* __restrict__ out, char* __restrict__ ws)
{
  unsigned* cnt = (unsigned*)(ws + 128);
  float* h0buf = (float*)(ws + 1024);
  float* h1buf = h0buf + 2048;
  float* f2buf = h1buf + 2048 + 2048 + 1024;      // skip ysbuf, f1buf
  u64* parts   = (u64*)(ws + 33792);

  const int tid = threadIdx.x, wg = blockIdx.x;
  const int wid = tid >> 6, lane = tid & 63;
  const bool isA = (wid < 4);
  const int j = wg*4 + (wid & 3);
  unsigned ph = 0;

  float wa[4][16], wb[4][16], bias[4], wx[4];
  if (isA){
    #pragma unroll
    for (int g = 0; g < 4; ++g){
      ld16(dWhh0 + (size_t)(j + g*1024)*1024 + lane*16, wa[g]);
      #pragma unroll
      for (int k = 0; k < 16; ++k) wb[g][k] = 0.f;
      wx[g]   = dWih0[j + g*1024];
      bias[g] = db0[j + g*1024];
    }
  } else {
    #pragma unroll
    for (int g = 0; g < 4; ++g){
      ld16(dWih1 + (size_t)(j + g*1024)*1024 + lane*16, wa[g]);
      ld16(dWhh1 + (size_t)(j + g*1024)*1024 + lane*16, wb[g]);
      bias[g] = db1[j + g*1024];
      wx[g] = 0.f;
    }
  }

  float c = f2buf[j];                 // h and c both init to f2
  if (lane == 0){
    if (isA) sto(&h0buf[j], c);
    else     sto(&h1buf[j], c);
  }
  const float y0f = (float)y[0];
  ph++; gbar(cnt, ph*NWG);

  __shared__ u64 sbest[8];

  for (int s = 0; s < NTY - 1; ++s){
    const int rp = s & 1, wp = rp ^ 1;

    // ---- phase A: layer0 cell (group A) ----
    if (isA){
      float xt;
      if (s == 0) xt = y0f;
      else {
        // redundant argmax reduction of 256 WG-partials (written last phase C)
        u64 b = 0ull;
        #pragma unroll
        for (int q = 0; q < 4; ++q){
          u64 v = __hip_atomic_load(&parts[lane + 64*q], __ATOMIC_RELAXED, __HIP_MEMORY_SCOPE_AGENT);
          if (v > b) b = v;
        }
        #pragma unroll
        for (int m = 32; m; m >>= 1){
          u64 v = __shfl_xor(b, m, 64);
          if (v > b) b = v;
        }
        unsigned row = ~(unsigned)(b & 0xFFFFFFFFull);
        xt = (float)row;
      }
      float hs[16]; coh16(h0buf + rp*1024 + lane*16, hs);
      float p[4];
      #pragma unroll
      for (int g = 0; g < 4; ++g){
        float sm = 0.f;
        #pragma unroll
        for (int k = 0; k < 16; ++k) sm += wa[g][k]*hs[k];
        p[g] = sm;
      }
      #pragma unroll
      for (int g = 0; g < 4; ++g) p[g] = wred(p[g]) + wx[g]*xt + bias[g];
      float ig = sigm(p[0]), fg = sigm(p[1]), gg = tanhf(p[2]), og = sigm(p[3]);
      c = fg*c + ig*gg;
      float hn = og * tanhf(c);
      if (lane == 0) sto(&h0buf[wp*1024 + j], hn);
    }
    ph++; gbar(cnt, ph*NWG);

    // ---- phase B: layer1 cell (group B) ----
    if (!isA){
      float u[16];  coh16(h0buf + wp*1024 + lane*16, u);
      float hs[16]; coh16(h1buf + rp*1024 + lane*16, hs);
      float p[4];
      #pragma unroll
      for (int g = 0; g < 4; ++g){
        float sm = 0.f;
        #pragma unroll
        for (int k = 0; k < 16; ++k) sm += wa[g][k]*u[k];
        #pragma unroll
        for (int k = 0; k < 16; ++k) sm += wb[g][k]*hs[k];
        p[g] = sm;
      }
      #pragma unroll
      for (int g = 0; g < 4; ++g) p[g] = wred(p[g]) + bias[g];
      float ig = sigm(p[0]), fg = sigm(p[1]), gg = tanhf(p[2]), og = sigm(p[3]);
      c = fg*c + ig*gg;
      float hn = og * tanhf(c);
      if (lane == 0) sto(&h1buf[wp*1024 + j], hn);
    }
    ph++; gbar(cnt, ph*NWG);

    // ---- phase C: logits row matvecs + partial argmax (all waves) ----
    {
      float hv[16]; coh16(h1buf + wp*1024 + lane*16, hv);
      u64 best = 0ull;
      float* orow = out + (size_t)(s + 1)*NV;
      for (int idx = wid; idx < 125; idx += 8){
        const int row = wg*125 + idx;
        float wv[16]; ld16(out_w + (size_t)row*1024 + lane*16, wv);
        float pp = 0.f;
        #pragma unroll
        for (int k = 0; k < 16; ++k) pp += wv[k]*hv[k];
        pp = wred(pp);
        float logit = pp + out_b[row];
        if (lane == 0) orow[row] = logit;
        unsigned bbits = __float_as_uint(logit);
        unsigned key = bbits ^ ((unsigned)(((int)bbits) >> 31) | 0x80000000u);
        u64 pk = ((u64)key << 32) | (u64)(unsigned)(~row);  // smaller row wins ties
        if (pk > best) best = pk;
      }
      if (lane == 0) sbest[wid] = best;
      __syncthreads();
      if (tid == 0){
        u64 m = sbest[0];
        #pragma unroll
        for (int q = 1; q < 8; ++q) if (sbest[q] > m) m = sbest[q];
        __hip_atomic_store(&parts[wg], m, __ATOMIC_RELAXED, __HIP_MEMORY_SCOPE_AGENT);
      }
    }
    ph++; gbar(cnt, ph*NWG);
  }
}

// ---------- final log-softmax over rows (row 0 = log_softmax(zeros)) ----------
__global__ void lsm_kernel(float* __restrict__ out){
  __shared__ float red[256];
  const int row = blockIdx.x, tid = threadIdx.x;
  float* r = out + (size_t)row*NV;
  if (row == 0){
    const float v = -logf((float)NV);
    for (int i = tid; i < NV; i += 256) r[i] = v;
    return;
  }
  float m = -1e30f;
  for (int i = tid; i < NV; i += 256) m = fmaxf(m, r[i]);
  red[tid] = m; __syncthreads();
  for (int st = 128; st; st >>= 1){ if (tid < st) red[tid] = fmaxf(red[tid], red[tid+st]); __syncthreads(); }
  m = red[0]; __syncthreads();
  float s = 0.f;
  for (int i = tid; i < NV; i += 256) s += expf(r[i] - m);
  red[tid] = s; __syncthreads();
  for (int st = 128; st; st >>= 1){ if (tid < st) red[tid] += red[tid+st]; __syncthreads(); }
  const float lse = m + logf(red[0]);
  __syncthreads();
  for (int i = tid; i < NV; i += 256) r[i] -= lse;
}

extern "C" void kernel_launch(void* const* d_in, const int* in_sizes, int n_in,
                              void* d_out, int out_size, void* d_ws, size_t ws_size,
                              hipStream_t stream)
{
  (void)in_sizes; (void)n_in; (void)out_size; (void)ws_size;
  const int*   x     = (const int*)  d_in[0];
  const int*   y     = (const int*)  d_in[1];
  const float* emb   = (const float*)d_in[2];
  const float* eWih0 = (const float*)d_in[3];
  const float* eWhh0 = (const float*)d_in[4];
  const float* eb0   = (const float*)d_in[5];
  const float* eWih1 = (const float*)d_in[6];
  const float* eWhh1 = (const float*)d_in[7];
  const float* eb1   = (const float*)d_in[8];
  const float* fc1w  = (const float*)d_in[9];
  const float* fc1b  = (const float*)d_in[10];
  const float* fc2w  = (const float*)d_in[11];
  const float* fc2b  = (const float*)d_in[12];
  const float* dWih0 = (const float*)d_in[13];
  const float* dWhh0 = (const float*)d_in[14];
  const float* db0   = (const float*)d_in[15];
  const float* dWih1 = (const float*)d_in[16];
  const float* dWhh1 = (const float*)d_in[17];
  const float* db1   = (const float*)d_in[18];
  const float* out_w = (const float*)d_in[19];
  const float* out_b = (const float*)d_in[20];
  float* out = (float*)d_out;
  char* ws = (char*)d_ws;

  hipMemsetAsync(ws, 0, 256, stream);   // zero both barrier counters (ws is re-poisoned each launch)
  enc_kernel<<<dim3(NWG), dim3(TPB), 0, stream>>>(x, emb, eWih0, eWhh0, eb0,
                                                  eWih1, eWhh1, eb1,
                                                  fc1w, fc1b, fc2w, fc2b, ws);
  dec_kernel<<<dim3(NWG), dim3(TPB), 0, stream>>>(y, dWih0, dWhh0, db0,
                                                  dWih1, dWhh1, db1,
                                                  out_w, out_b, out, ws);
  lsm_kernel<<<dim3(NTY), dim3(256), 0, stream>>>(out);
}